// Round 1
// 1085.204 us; speedup vs baseline: 1.1056x; 1.1056x over previous
//
#include <hip/hip_runtime.h>
#include <hip/hip_bf16.h>

#define B_ 4
#define H_ 32
#define S_ 2048
#define D_ 128
#define DM_ 4096
#define BH_ (B_*H_)
#define M_ (B_*S_)   // 8192 rows of final GEMM

typedef short bf16x8 __attribute__((ext_vector_type(8)));
typedef float f32x4 __attribute__((ext_vector_type(4)));

__device__ __forceinline__ float phi_f(float x) {
    // elu(x)+1
    return x > 0.f ? x + 1.f : __expf(x);
}

__device__ __forceinline__ void gl_lds16(void* lds_uniform, const void* gptr) {
    __builtin_amdgcn_global_load_lds(
        (const __attribute__((address_space(1))) void*)gptr,
        (__attribute__((address_space(3))) void*)lds_uniform,
        16, 0, 0);
}

// ---------------------------------------------------------------------------
// K1: memory[bh][k][v] = sum_s phi(K[bh][s][k]) * V[bh][s][v]
//     norm[bh][k]      = sum_s phi(K[bh][s][k])
// grid (4 splits, 128 bh), block 256. Register tile 4k x 16v per thread.
// ---------------------------------------------------------------------------
__global__ __launch_bounds__(256) void k1_memory(
    const float* __restrict__ Kin, const float* __restrict__ Vin,
    float* __restrict__ mem, float* __restrict__ nrm)
{
    const int split = blockIdx.x;   // 0..3, 512 rows each
    const int bh = blockIdx.y;
    const int tid = threadIdx.x;
    const int kg = tid >> 3, vg = tid & 7;
    const int k0 = kg * 4;

    __shared__ float sK[8][128];
    __shared__ float sV[8][128];

    float acc[4][16];
#pragma unroll
    for (int i = 0; i < 4; ++i)
#pragma unroll
        for (int j = 0; j < 16; ++j) acc[i][j] = 0.f;
    float na[4] = {0.f, 0.f, 0.f, 0.f};

    const long base = (long)bh * S_ * D_ + (long)split * (S_/4) * D_;
    const float* Kp = Kin + base;
    const float* Vp = Vin + base;

    const int lrow = tid >> 5;          // 0..7
    const int lcol = (tid & 31) * 4;

    for (int c = 0; c < (S_/4)/8; ++c) {   // 64 chunks of 8 rows
        float4 kv = *(const float4*)(Kp + (long)(c*8 + lrow)*D_ + lcol);
        float4 vv = *(const float4*)(Vp + (long)(c*8 + lrow)*D_ + lcol);
        float4 pk = make_float4(phi_f(kv.x), phi_f(kv.y), phi_f(kv.z), phi_f(kv.w));
        __syncthreads();                   // previous iter readers done
        *(float4*)&sK[lrow][lcol] = pk;
        *(float4*)&sV[lrow][lcol] = vv;
        __syncthreads();
#pragma unroll
        for (int s = 0; s < 8; ++s) {
            float a[4];
            *(float4*)a = *(const float4*)&sK[s][k0];
            float bb[16];
#pragma unroll
            for (int j = 0; j < 4; ++j)
                *(float4*)&bb[j*4] = *(const float4*)&sV[s][vg*4 + j*32];
            if (vg == 0) {
#pragma unroll
                for (int i = 0; i < 4; ++i) na[i] += a[i];
            }
#pragma unroll
            for (int i = 0; i < 4; ++i)
#pragma unroll
                for (int j = 0; j < 16; ++j)
                    acc[i][j] += a[i] * bb[j];
        }
    }
    float* mp = mem + (long)bh * D_ * D_;
#pragma unroll
    for (int i = 0; i < 4; ++i)
#pragma unroll
        for (int j = 0; j < 16; ++j) {
            int v = vg*4 + (j>>2)*32 + (j&3);
            atomicAdd(&mp[(k0+i)*D_ + v], acc[i][j]);
        }
    if (vg == 0) {
        float* np = nrm + bh * D_;
#pragma unroll
        for (int i = 0; i < 4; ++i) atomicAdd(&np[k0+i], na[i]);
    }
}

// ---------------------------------------------------------------------------
// K2: retrieved = phi(Q) @ mem ; denom = phi(Q)·norm ;
//     attn = gw*retrieved/denom + lw*local ; write bf16 to [B,S,H*D]
// grid (64 s-chunks of 32 rows, 128 bh), block 256.
// ---------------------------------------------------------------------------
__global__ __launch_bounds__(256) void k2_retrieve(
    const float* __restrict__ Qin, const float* __restrict__ Lin,
    const float* __restrict__ bal,
    const float* __restrict__ mem, const float* __restrict__ nrm,
    __hip_bfloat16* __restrict__ attnB)
{
    const int sc = blockIdx.x;    // 0..63
    const int bh = blockIdx.y;
    const int b = bh >> 5, h = bh & 31;
    const int tid = threadIdx.x;

    __shared__ float sQ[32][128];
    __shared__ float sN[128];
    __shared__ float sDenP[32][8];
    __shared__ float sDen[32];

    const float* Qp = Qin + (long)bh*S_*D_ + (long)sc*32*D_;
    const float* Lp = Lin + (long)bh*S_*D_ + (long)sc*32*D_;
    const float* mp = mem + (long)bh*D_*D_;

#pragma unroll
    for (int i = 0; i < 4; ++i) {
        int c = i*256 + tid;               // float4 chunk 0..1023
        float4 q = *(const float4*)(Qp + (long)c*4);
        float4 p = make_float4(phi_f(q.x), phi_f(q.y), phi_f(q.z), phi_f(q.w));
        ((float4*)sQ)[c] = p;
    }
    if (tid < 128) sN[tid] = nrm[bh*D_ + tid];
    __syncthreads();

    {
        int row = tid >> 3, pt = tid & 7;
        float p = 0.f;
#pragma unroll
        for (int kk = 0; kk < 16; ++kk) {
            int k = pt*16 + kk;
            p += sQ[row][k] * sN[k];
        }
        sDenP[row][pt] = p;
    }
    __syncthreads();
    if (tid < 32) {
        float d = 0.f;
#pragma unroll
        for (int j = 0; j < 8; ++j) d += sDenP[tid][j];
        sDen[tid] = d;
    }
    __syncthreads();

    const int vg = tid & 31, rg = tid >> 5;
    const int v0 = vg*4, r0 = rg*4;
    float acc[4][4];
#pragma unroll
    for (int r = 0; r < 4; ++r)
#pragma unroll
        for (int j = 0; j < 4; ++j) acc[r][j] = 0.f;

#pragma unroll 8
    for (int k = 0; k < 128; ++k) {
        float4 m = *(const float4*)(mp + k*D_ + v0);
#pragma unroll
        for (int r = 0; r < 4; ++r) {
            float q = sQ[r0+r][k];
            acc[r][0] += q*m.x; acc[r][1] += q*m.y;
            acc[r][2] += q*m.z; acc[r][3] += q*m.w;
        }
    }

    float bv = bal[h];
    float gw = 1.f/(1.f+__expf(-bv));
    float lw = 1.f/(1.f+__expf(-(1.f-bv)));
#pragma unroll
    for (int r = 0; r < 4; ++r) {
        int row = r0 + r;
        float scale = gw / sDen[row];
        float4 lv = *(const float4*)(Lp + (long)row*D_ + v0);
        float o0 = acc[r][0]*scale + lw*lv.x;
        float o1 = acc[r][1]*scale + lw*lv.y;
        float o2 = acc[r][2]*scale + lw*lv.z;
        float o3 = acc[r][3]*scale + lw*lv.w;
        __hip_bfloat16 ob[4] = {__float2bfloat16(o0), __float2bfloat16(o1),
                                __float2bfloat16(o2), __float2bfloat16(o3)};
        long oidx = ((long)b*S_ + sc*32 + row)*DM_ + h*D_ + v0;
        *(uint2*)(attnB + oidx) = *(uint2*)ob;
    }
}

// ---------------------------------------------------------------------------
// w_o fp32 -> bf16
// ---------------------------------------------------------------------------
__global__ __launch_bounds__(256) void kconv(
    const float* __restrict__ w, __hip_bfloat16* __restrict__ wb)
{
    long i = ((long)blockIdx.x*256 + threadIdx.x)*4;
    float4 f = *(const float4*)(w + i);
    __hip_bfloat16 ob[4] = {__float2bfloat16(f.x), __float2bfloat16(f.y),
                            __float2bfloat16(f.z), __float2bfloat16(f.w)};
    *(uint2*)(wb + i) = *(uint2*)ob;
}

// ---------------------------------------------------------------------------
// K3: Y[8192,4096] = X[8192,4096] @ W[4096,4096]^T   (bf16 MFMA, fp32 out)
// 256x256 8-phase template (m201): BK=64, 8 waves (2Mx4N), 512 threads,
// 128 KiB LDS dbuf, st_16x32 swizzle via pre-swizzled global source,
// counted vmcnt(8) at tile boundaries (never 0 in steady state),
// raw s_barrier (no __syncthreads -> no vmcnt drain), setprio around MFMA.
// ---------------------------------------------------------------------------
#define GBM 256
#define GBN 256
#define GBK 64
#define GNT (DM_/GBK)   // 64 K-tiles

// Swizzled LDS read: logical (row,k) lives at physical row*64 + (k ^ ((row>>2)&1)<<4)
// (st_16x32: byte ^= ((byte>>9)&1)<<5 on the [256][64]bf16 = [256][128B] tile)
__device__ __forceinline__ bf16x8 ldfrag(const __hip_bfloat16* base, int row, int k) {
    const int kk = k ^ (((row >> 2) & 1) << 4);
    return *(const bf16x8*)(base + row * GBK + kk);
}

// Stage one 256x64 K-tile of A and B into LDS buffers.
// LDS dest is linear (gl_lds requirement: uniform base + lane*16);
// the SOURCE chunk index is pre-swizzled with the same involution, so the
// swizzled ldfrag reads see the right data. 8 loads/thread.
__device__ __forceinline__ void stage_tile(
    const __hip_bfloat16* __restrict__ X, const __hip_bfloat16* __restrict__ W,
    __hip_bfloat16* sAb, __hip_bfloat16* sBb,
    int m0, int n0, int kb, int wave, int lane)
{
#pragma unroll
    for (int r = 0; r < 4; ++r) {
        const int c  = r * 512 + wave * 64 + lane;         // 16B chunk id 0..2047
        const int cp = c ^ (((c >> 5) & 1) << 1);          // chunk-level st_16x32
        const int row = cp >> 3, ko = (cp & 7) * 8;
        gl_lds16((void*)(sAb + (r * 512 + wave * 64) * 8),
                 (const void*)(X + (long)(m0 + row) * DM_ + kb + ko));
    }
#pragma unroll
    for (int r = 0; r < 4; ++r) {
        const int c  = r * 512 + wave * 64 + lane;
        const int cp = c ^ (((c >> 5) & 1) << 1);
        const int row = cp >> 3, ko = (cp & 7) * 8;
        gl_lds16((void*)(sBb + (r * 512 + wave * 64) * 8),
                 (const void*)(W + (long)(n0 + row) * DM_ + kb + ko));
    }
}

__global__ __launch_bounds__(512, 2) void k3_gemm(
    const __hip_bfloat16* __restrict__ X,
    const __hip_bfloat16* __restrict__ W,
    float* __restrict__ Y)
{
    __shared__ alignas(16) __hip_bfloat16 sA[2][GBM * GBK];   // 64 KiB
    __shared__ alignas(16) __hip_bfloat16 sB[2][GBN * GBK];   // 64 KiB

    const int tid = threadIdx.x;
    const int wave = tid >> 6, lane = tid & 63;
    const int lm = lane & 15, quad = lane >> 4;
    const int wm = wave >> 2, wn = wave & 3;     // 2M x 4N waves

    // bijective XCD chunk swizzle: 512 wgs, 512 % 8 == 0
    const int orig = blockIdx.x;
    const int wg = (orig & 7) * 64 + (orig >> 3);
    const int m0 = (wg >> 4) * GBM;              // 32 m-tiles (n-fast order)
    const int n0 = (wg & 15) * GBN;              // 16 n-tiles

    f32x4 acc[8][4];
#pragma unroll
    for (int i = 0; i < 8; ++i)
#pragma unroll
        for (int j = 0; j < 4; ++j) { f32x4 z = {0.f,0.f,0.f,0.f}; acc[i][j] = z; }

    const int ar0 = wm * 128 + lm;               // A row base (+ mh*64 + mf*16)
    const int br0 = wn * 64 + lm;                // B row base (+ nf*16)
    const int kq  = quad * 8;

    // prologue: tiles 0 and 1 in flight; wait tile 0 only (counted)
    stage_tile(X, W, sA[0], sB[0], m0, n0, 0, wave, lane);
    stage_tile(X, W, sA[1], sB[1], m0, n0, GBK, wave, lane);
    asm volatile("s_waitcnt vmcnt(8)" ::: "memory");
    __builtin_amdgcn_s_barrier();

    bf16x8 a[4][2], b[4][2];

    for (int t = 0; t < GNT; ++t) {
        const int cur = t & 1;
        const __hip_bfloat16* As = sA[cur];
        const __hip_bfloat16* Bs = sB[cur];

        // ---- phase 0: ds_read A(mh0)x2kh (8) + B(n0,n1)x2kh (4); MFMA quad (mh0, n0-1)
#pragma unroll
        for (int mf = 0; mf < 4; ++mf)
#pragma unroll
            for (int kh = 0; kh < 2; ++kh)
                a[mf][kh] = ldfrag(As, ar0 + mf * 16, kh * 32 + kq);
#pragma unroll
        for (int nf = 0; nf < 2; ++nf)
#pragma unroll
            for (int kh = 0; kh < 2; ++kh)
                b[nf][kh] = ldfrag(Bs, br0 + nf * 16, kh * 32 + kq);
        __builtin_amdgcn_s_barrier();
        asm volatile("s_waitcnt lgkmcnt(0)" ::: "memory");
        __builtin_amdgcn_sched_barrier(0);
        __builtin_amdgcn_s_setprio(1);
#pragma unroll
        for (int mf = 0; mf < 4; ++mf)
#pragma unroll
            for (int nf = 0; nf < 2; ++nf)
#pragma unroll
                for (int kh = 0; kh < 2; ++kh)
                    acc[mf][nf] = __builtin_amdgcn_mfma_f32_16x16x32_bf16(
                        a[mf][kh], b[nf][kh], acc[mf][nf], 0, 0, 0);
        __builtin_amdgcn_s_setprio(0);
        __builtin_amdgcn_s_barrier();

        // ---- phase 1: ds_read B(n2,n3) (4); MFMA quad (mh0, n2-3)
#pragma unroll
        for (int nf = 2; nf < 4; ++nf)
#pragma unroll
            for (int kh = 0; kh < 2; ++kh)
                b[nf][kh] = ldfrag(Bs, br0 + nf * 16, kh * 32 + kq);
        __builtin_amdgcn_s_barrier();
        asm volatile("s_waitcnt lgkmcnt(0)" ::: "memory");
        __builtin_amdgcn_sched_barrier(0);
        __builtin_amdgcn_s_setprio(1);
#pragma unroll
        for (int mf = 0; mf < 4; ++mf)
#pragma unroll
            for (int nf = 2; nf < 4; ++nf)
#pragma unroll
                for (int kh = 0; kh < 2; ++kh)
                    acc[mf][nf] = __builtin_amdgcn_mfma_f32_16x16x32_bf16(
                        a[mf][kh], b[nf][kh], acc[mf][nf], 0, 0, 0);
        __builtin_amdgcn_s_setprio(0);
        __builtin_amdgcn_s_barrier();

        // ---- phase 2: ds_read A(mh1)x2kh (8, overwrite a); MFMA quad (mh1, n0-1)
#pragma unroll
        for (int mf = 0; mf < 4; ++mf)
#pragma unroll
            for (int kh = 0; kh < 2; ++kh)
                a[mf][kh] = ldfrag(As, ar0 + 64 + mf * 16, kh * 32 + kq);
        __builtin_amdgcn_s_barrier();
        asm volatile("s_waitcnt lgkmcnt(0)" ::: "memory");
        __builtin_amdgcn_sched_barrier(0);
        __builtin_amdgcn_s_setprio(1);
#pragma unroll
        for (int mf = 0; mf < 4; ++mf)
#pragma unroll
            for (int nf = 0; nf < 2; ++nf)
#pragma unroll
                for (int kh = 0; kh < 2; ++kh)
                    acc[4 + mf][nf] = __builtin_amdgcn_mfma_f32_16x16x32_bf16(
                        a[mf][kh], b[nf][kh], acc[4 + mf][nf], 0, 0, 0);
        __builtin_amdgcn_s_setprio(0);
        __builtin_amdgcn_s_barrier();

        // ---- phase 3: stage tile t+2 into buf cur (all reads of cur are done:
        // p0-p2 ds_reads completed before p2's MFMA, barrier crossed). No ds_reads.
        // MFMA quad (mh1, n2-3). Boundary: counted vmcnt(8) -> tile t+1 landed,
        // t+2's 8 loads stay in flight across the barrier.
        if (t + 2 < GNT)
            stage_tile(X, W, sA[cur], sB[cur], m0, n0, (t + 2) * GBK, wave, lane);
        __builtin_amdgcn_s_barrier();
        __builtin_amdgcn_s_setprio(1);
#pragma unroll
        for (int mf = 0; mf < 4; ++mf)
#pragma unroll
            for (int nf = 2; nf < 4; ++nf)
#pragma unroll
                for (int kh = 0; kh < 2; ++kh)
                    acc[4 + mf][nf] = __builtin_amdgcn_mfma_f32_16x16x32_bf16(
                        a[mf][kh], b[nf][kh], acc[4 + mf][nf], 0, 0, 0);
        __builtin_amdgcn_s_setprio(0);
        if (t + 2 < GNT)
            asm volatile("s_waitcnt vmcnt(8)" ::: "memory");
        else
            asm volatile("s_waitcnt vmcnt(0)" ::: "memory");
        __builtin_amdgcn_s_barrier();
    }

    // epilogue: C/D layout col=lane&15, row=quad*4+reg
#pragma unroll
    for (int mf = 0; mf < 8; ++mf) {
        const int row = m0 + wm * 128 + mf * 16 + quad * 4;
#pragma unroll
        for (int nf = 0; nf < 4; ++nf) {
            const int col = n0 + wn * 64 + nf * 16 + lm;
#pragma unroll
            for (int r = 0; r < 4; ++r)
                Y[(long)(row + r) * DM_ + col] = acc[mf][nf][r];
        }
    }
}

// ---------------------------------------------------------------------------
extern "C" void kernel_launch(void* const* d_in, const int* in_sizes, int n_in,
                              void* d_out, int out_size, void* d_ws, size_t ws_size,
                              hipStream_t stream) {
    const float* Q   = (const float*)d_in[0];
    const float* K   = (const float*)d_in[1];
    const float* V   = (const float*)d_in[2];
    const float* L   = (const float*)d_in[3];
    const float* bal = (const float*)d_in[4];
    const float* Wo  = (const float*)d_in[5];
    float* Y = (float*)d_out;

    char* ws = (char*)d_ws;
    float* memory = (float*)ws;                                  // 8,388,608 B
    float* norm   = (float*)(ws + 8388608);                      //    65,536 B
    __hip_bfloat16* attnB = (__hip_bfloat16*)(ws + 8454144);     // 67,108,864 B
    __hip_bfloat16* woB   = (__hip_bfloat16*)(ws + 75563008);    // 33,554,432 B

    // zero the atomic accumulators (ws is poisoned 0xAA before every launch)
    hipMemsetAsync(memory, 0, 8454144, stream);

    k1_memory<<<dim3(4, BH_), 256, 0, stream>>>(K, V, memory, norm);
    kconv<<<DM_*DM_/4/256, 256, 0, stream>>>(Wo, woB);
    k2_retrieve<<<dim3(S_/32, BH_), 256, 0, stream>>>(Q, L, bal, memory, norm, attnB);
    k3_gemm<<<dim3(512), 512, 0, stream>>>(attnB, woB, Y);
}

// Round 2
// 1074.000 us; speedup vs baseline: 1.1171x; 1.0104x over previous
//
#include <hip/hip_runtime.h>
#include <hip/hip_bf16.h>

#define B_ 4
#define H_ 32
#define S_ 2048
#define D_ 128
#define DM_ 4096
#define BH_ (B_*H_)
#define M_ (B_*S_)   // 8192 rows of final GEMM

typedef short bf16x8 __attribute__((ext_vector_type(8)));
typedef float f32x4 __attribute__((ext_vector_type(4)));

__device__ __forceinline__ float phi_f(float x) {
    // elu(x)+1
    return x > 0.f ? x + 1.f : __expf(x);
}

__device__ __forceinline__ void gl_lds16(void* lds_uniform, const void* gptr) {
    __builtin_amdgcn_global_load_lds(
        (const __attribute__((address_space(1))) void*)gptr,
        (__attribute__((address_space(3))) void*)lds_uniform,
        16, 0, 0);
}

// ---------------------------------------------------------------------------
// K1: memory[bh][k][v] = sum_s phi(K[bh][s][k]) * V[bh][s][v]
//     norm[bh][k]      = sum_s phi(K[bh][s][k])
// grid (4 splits, 128 bh), block 256. Register tile 4k x 16v per thread.
// ---------------------------------------------------------------------------
__global__ __launch_bounds__(256) void k1_memory(
    const float* __restrict__ Kin, const float* __restrict__ Vin,
    float* __restrict__ mem, float* __restrict__ nrm)
{
    const int split = blockIdx.x;   // 0..3, 512 rows each
    const int bh = blockIdx.y;
    const int tid = threadIdx.x;
    const int kg = tid >> 3, vg = tid & 7;
    const int k0 = kg * 4;

    __shared__ float sK[8][128];
    __shared__ float sV[8][128];

    float acc[4][16];
#pragma unroll
    for (int i = 0; i < 4; ++i)
#pragma unroll
        for (int j = 0; j < 16; ++j) acc[i][j] = 0.f;
    float na[4] = {0.f, 0.f, 0.f, 0.f};

    const long base = (long)bh * S_ * D_ + (long)split * (S_/4) * D_;
    const float* Kp = Kin + base;
    const float* Vp = Vin + base;

    const int lrow = tid >> 5;          // 0..7
    const int lcol = (tid & 31) * 4;

    for (int c = 0; c < (S_/4)/8; ++c) {   // 64 chunks of 8 rows
        float4 kv = *(const float4*)(Kp + (long)(c*8 + lrow)*D_ + lcol);
        float4 vv = *(const float4*)(Vp + (long)(c*8 + lrow)*D_ + lcol);
        float4 pk = make_float4(phi_f(kv.x), phi_f(kv.y), phi_f(kv.z), phi_f(kv.w));
        __syncthreads();                   // previous iter readers done
        *(float4*)&sK[lrow][lcol] = pk;
        *(float4*)&sV[lrow][lcol] = vv;
        __syncthreads();
#pragma unroll
        for (int s = 0; s < 8; ++s) {
            float a[4];
            *(float4*)a = *(const float4*)&sK[s][k0];
            float bb[16];
#pragma unroll
            for (int j = 0; j < 4; ++j)
                *(float4*)&bb[j*4] = *(const float4*)&sV[s][vg*4 + j*32];
            if (vg == 0) {
#pragma unroll
                for (int i = 0; i < 4; ++i) na[i] += a[i];
            }
#pragma unroll
            for (int i = 0; i < 4; ++i)
#pragma unroll
                for (int j = 0; j < 16; ++j)
                    acc[i][j] += a[i] * bb[j];
        }
    }
    float* mp = mem + (long)bh * D_ * D_;
#pragma unroll
    for (int i = 0; i < 4; ++i)
#pragma unroll
        for (int j = 0; j < 16; ++j) {
            int v = vg*4 + (j>>2)*32 + (j&3);
            atomicAdd(&mp[(k0+i)*D_ + v], acc[i][j]);
        }
    if (vg == 0) {
        float* np = nrm + bh * D_;
#pragma unroll
        for (int i = 0; i < 4; ++i) atomicAdd(&np[k0+i], na[i]);
    }
}

// ---------------------------------------------------------------------------
// K2: retrieved = phi(Q) @ mem ; denom = phi(Q)·norm ;
//     attn = gw*retrieved/denom + lw*local ; write bf16 to [B,S,H*D]
// grid (64 s-chunks of 32 rows, 128 bh), block 256.
// ---------------------------------------------------------------------------
__global__ __launch_bounds__(256) void k2_retrieve(
    const float* __restrict__ Qin, const float* __restrict__ Lin,
    const float* __restrict__ bal,
    const float* __restrict__ mem, const float* __restrict__ nrm,
    __hip_bfloat16* __restrict__ attnB)
{
    const int sc = blockIdx.x;    // 0..63
    const int bh = blockIdx.y;
    const int b = bh >> 5, h = bh & 31;
    const int tid = threadIdx.x;

    __shared__ float sQ[32][128];
    __shared__ float sN[128];
    __shared__ float sDenP[32][8];
    __shared__ float sDen[32];

    const float* Qp = Qin + (long)bh*S_*D_ + (long)sc*32*D_;
    const float* Lp = Lin + (long)bh*S_*D_ + (long)sc*32*D_;
    const float* mp = mem + (long)bh*D_*D_;

#pragma unroll
    for (int i = 0; i < 4; ++i) {
        int c = i*256 + tid;               // float4 chunk 0..1023
        float4 q = *(const float4*)(Qp + (long)c*4);
        float4 p = make_float4(phi_f(q.x), phi_f(q.y), phi_f(q.z), phi_f(q.w));
        ((float4*)sQ)[c] = p;
    }
    if (tid < 128) sN[tid] = nrm[bh*D_ + tid];
    __syncthreads();

    {
        int row = tid >> 3, pt = tid & 7;
        float p = 0.f;
#pragma unroll
        for (int kk = 0; kk < 16; ++kk) {
            int k = pt*16 + kk;
            p += sQ[row][k] * sN[k];
        }
        sDenP[row][pt] = p;
    }
    __syncthreads();
    if (tid < 32) {
        float d = 0.f;
#pragma unroll
        for (int j = 0; j < 8; ++j) d += sDenP[tid][j];
        sDen[tid] = d;
    }
    __syncthreads();

    const int vg = tid & 31, rg = tid >> 5;
    const int v0 = vg*4, r0 = rg*4;
    float acc[4][4];
#pragma unroll
    for (int r = 0; r < 4; ++r)
#pragma unroll
        for (int j = 0; j < 4; ++j) acc[r][j] = 0.f;

#pragma unroll 8
    for (int k = 0; k < 128; ++k) {
        float4 m = *(const float4*)(mp + k*D_ + v0);
#pragma unroll
        for (int r = 0; r < 4; ++r) {
            float q = sQ[r0+r][k];
            acc[r][0] += q*m.x; acc[r][1] += q*m.y;
            acc[r][2] += q*m.z; acc[r][3] += q*m.w;
        }
    }

    float bv = bal[h];
    float gw = 1.f/(1.f+__expf(-bv));
    float lw = 1.f/(1.f+__expf(-(1.f-bv)));
#pragma unroll
    for (int r = 0; r < 4; ++r) {
        int row = r0 + r;
        float scale = gw / sDen[row];
        float4 lv = *(const float4*)(Lp + (long)row*D_ + v0);
        float o0 = acc[r][0]*scale + lw*lv.x;
        float o1 = acc[r][1]*scale + lw*lv.y;
        float o2 = acc[r][2]*scale + lw*lv.z;
        float o3 = acc[r][3]*scale + lw*lv.w;
        __hip_bfloat16 ob[4] = {__float2bfloat16(o0), __float2bfloat16(o1),
                                __float2bfloat16(o2), __float2bfloat16(o3)};
        long oidx = ((long)b*S_ + sc*32 + row)*DM_ + h*D_ + v0;
        *(uint2*)(attnB + oidx) = *(uint2*)ob;
    }
}

// ---------------------------------------------------------------------------
// w_o fp32 -> bf16
// ---------------------------------------------------------------------------
__global__ __launch_bounds__(256) void kconv(
    const float* __restrict__ w, __hip_bfloat16* __restrict__ wb)
{
    long i = ((long)blockIdx.x*256 + threadIdx.x)*4;
    float4 f = *(const float4*)(w + i);
    __hip_bfloat16 ob[4] = {__float2bfloat16(f.x), __float2bfloat16(f.y),
                            __float2bfloat16(f.z), __float2bfloat16(f.w)};
    *(uint2*)(wb + i) = *(uint2*)ob;
}

// ---------------------------------------------------------------------------
// K3: Y[8192,4096] = X[8192,4096] @ W[4096,4096]^T   (bf16 MFMA, fp32 out)
// 256x256 8-phase template (m201): BK=64, 8 waves (2Mx4N), 512 threads,
// 128 KiB LDS dbuf, counted vmcnt(8) at tile boundaries (never 0 in steady
// state), raw s_barrier (no vmcnt drain), setprio around MFMA.
//
// Swizzle (fixed in R1): tile rows are 64 bf16 = 128 B = exactly 32 banks, so
// every row starts at bank 0. A single-bit XOR only spreads reads over 2 of
// the 8 16B-segments -> 4-8 way conflicts (R0: 2.5e7 conflicts, MfmaUtil 32%).
// Correct recipe: permute the 16B-segment index by THREE row bits:
//   seg' = seg ^ (row & 7)   (byte ^= (row&7)<<4)
// One ds_read_b128 instruction (16 lanes, rows lm=0..15, fixed k) then covers
// all 8 segment positions exactly twice -> 2-way aliasing = free (m136).
// global_load_lds dest stays linear; the SOURCE chunk applies the same
// involution so read-side and write-side permutations match (m201 pattern).
// ---------------------------------------------------------------------------
#define GBM 256
#define GBN 256
#define GBK 64
#define GNT (DM_/GBK)   // 64 K-tiles

// Swizzled LDS read: logical (row,k) -> physical element row*64 + (k ^ ((row&7)<<3))
// (k is always a multiple of 8 at call sites, so this XOR only permutes the
// 16B-segment index.)
__device__ __forceinline__ bf16x8 ldfrag(const __hip_bfloat16* base, int row, int k) {
    const int kk = k ^ ((row & 7) << 3);
    return *(const bf16x8*)(base + row * GBK + kk);
}

// Stage one 256x64 K-tile of A and B into LDS buffers.
// LDS dest is linear (gl_lds requirement: uniform base + lane*16); physical
// chunk c (row = c>>3, physSeg = c&7) must hold logical segment
// physSeg ^ (row&7), so the source address is pre-swizzled with the same
// involution the reads use. 8 loads/thread.
__device__ __forceinline__ void stage_tile(
    const __hip_bfloat16* __restrict__ X, const __hip_bfloat16* __restrict__ W,
    __hip_bfloat16* sAb, __hip_bfloat16* sBb,
    int m0, int n0, int kb, int wave, int lane)
{
#pragma unroll
    for (int r = 0; r < 4; ++r) {
        const int c   = r * 512 + wave * 64 + lane;        // 16B chunk id 0..2047
        const int row = c >> 3;
        const int ko  = ((c & 7) ^ (row & 7)) * 8;         // pre-swizzled source seg
        gl_lds16((void*)(sAb + (r * 512 + wave * 64) * 8),
                 (const void*)(X + (long)(m0 + row) * DM_ + kb + ko));
    }
#pragma unroll
    for (int r = 0; r < 4; ++r) {
        const int c   = r * 512 + wave * 64 + lane;
        const int row = c >> 3;
        const int ko  = ((c & 7) ^ (row & 7)) * 8;
        gl_lds16((void*)(sBb + (r * 512 + wave * 64) * 8),
                 (const void*)(W + (long)(n0 + row) * DM_ + kb + ko));
    }
}

__global__ __launch_bounds__(512, 2) void k3_gemm(
    const __hip_bfloat16* __restrict__ X,
    const __hip_bfloat16* __restrict__ W,
    float* __restrict__ Y)
{
    __shared__ alignas(16) __hip_bfloat16 sA[2][GBM * GBK];   // 64 KiB
    __shared__ alignas(16) __hip_bfloat16 sB[2][GBN * GBK];   // 64 KiB

    const int tid = threadIdx.x;
    const int wave = tid >> 6, lane = tid & 63;
    const int lm = lane & 15, quad = lane >> 4;
    const int wm = wave >> 2, wn = wave & 3;     // 2M x 4N waves

    // bijective XCD chunk swizzle: 512 wgs, 512 % 8 == 0
    const int orig = blockIdx.x;
    const int wg = (orig & 7) * 64 + (orig >> 3);
    const int m0 = (wg >> 4) * GBM;              // 32 m-tiles (n-fast order)
    const int n0 = (wg & 15) * GBN;              // 16 n-tiles

    f32x4 acc[8][4];
#pragma unroll
    for (int i = 0; i < 8; ++i)
#pragma unroll
        for (int j = 0; j < 4; ++j) { f32x4 z = {0.f,0.f,0.f,0.f}; acc[i][j] = z; }

    const int ar0 = wm * 128 + lm;               // A row base (+ mh*64 + mf*16)
    const int br0 = wn * 64 + lm;                // B row base (+ nf*16)
    const int kq  = quad * 8;

    // prologue: tiles 0 and 1 in flight; wait tile 0 only (counted)
    stage_tile(X, W, sA[0], sB[0], m0, n0, 0, wave, lane);
    stage_tile(X, W, sA[1], sB[1], m0, n0, GBK, wave, lane);
    asm volatile("s_waitcnt vmcnt(8)" ::: "memory");
    __builtin_amdgcn_s_barrier();

    bf16x8 a[4][2], b[4][2];

    for (int t = 0; t < GNT; ++t) {
        const int cur = t & 1;
        const __hip_bfloat16* As = sA[cur];
        const __hip_bfloat16* Bs = sB[cur];

        // ---- phase 0: ds_read A(mh0)x2kh (8) + B(n0,n1)x2kh (4); MFMA quad (mh0, n0-1)
#pragma unroll
        for (int mf = 0; mf < 4; ++mf)
#pragma unroll
            for (int kh = 0; kh < 2; ++kh)
                a[mf][kh] = ldfrag(As, ar0 + mf * 16, kh * 32 + kq);
#pragma unroll
        for (int nf = 0; nf < 2; ++nf)
#pragma unroll
            for (int kh = 0; kh < 2; ++kh)
                b[nf][kh] = ldfrag(Bs, br0 + nf * 16, kh * 32 + kq);
        __builtin_amdgcn_s_barrier();
        asm volatile("s_waitcnt lgkmcnt(0)" ::: "memory");
        __builtin_amdgcn_sched_barrier(0);
        __builtin_amdgcn_s_setprio(1);
#pragma unroll
        for (int mf = 0; mf < 4; ++mf)
#pragma unroll
            for (int nf = 0; nf < 2; ++nf)
#pragma unroll
                for (int kh = 0; kh < 2; ++kh)
                    acc[mf][nf] = __builtin_amdgcn_mfma_f32_16x16x32_bf16(
                        a[mf][kh], b[nf][kh], acc[mf][nf], 0, 0, 0);
        __builtin_amdgcn_s_setprio(0);
        __builtin_amdgcn_s_barrier();

        // ---- phase 1: ds_read B(n2,n3) (4); MFMA quad (mh0, n2-3)
#pragma unroll
        for (int nf = 2; nf < 4; ++nf)
#pragma unroll
            for (int kh = 0; kh < 2; ++kh)
                b[nf][kh] = ldfrag(Bs, br0 + nf * 16, kh * 32 + kq);
        __builtin_amdgcn_s_barrier();
        asm volatile("s_waitcnt lgkmcnt(0)" ::: "memory");
        __builtin_amdgcn_sched_barrier(0);
        __builtin_amdgcn_s_setprio(1);
#pragma unroll
        for (int mf = 0; mf < 4; ++mf)
#pragma unroll
            for (int nf = 2; nf < 4; ++nf)
#pragma unroll
                for (int kh = 0; kh < 2; ++kh)
                    acc[mf][nf] = __builtin_amdgcn_mfma_f32_16x16x32_bf16(
                        a[mf][kh], b[nf][kh], acc[mf][nf], 0, 0, 0);
        __builtin_amdgcn_s_setprio(0);
        __builtin_amdgcn_s_barrier();

        // ---- phase 2: ds_read A(mh1)x2kh (8, overwrite a); MFMA quad (mh1, n0-1)
#pragma unroll
        for (int mf = 0; mf < 4; ++mf)
#pragma unroll
            for (int kh = 0; kh < 2; ++kh)
                a[mf][kh] = ldfrag(As, ar0 + 64 + mf * 16, kh * 32 + kq);
        __builtin_amdgcn_s_barrier();
        asm volatile("s_waitcnt lgkmcnt(0)" ::: "memory");
        __builtin_amdgcn_sched_barrier(0);
        __builtin_amdgcn_s_setprio(1);
#pragma unroll
        for (int mf = 0; mf < 4; ++mf)
#pragma unroll
            for (int nf = 0; nf < 2; ++nf)
#pragma unroll
                for (int kh = 0; kh < 2; ++kh)
                    acc[4 + mf][nf] = __builtin_amdgcn_mfma_f32_16x16x32_bf16(
                        a[mf][kh], b[nf][kh], acc[4 + mf][nf], 0, 0, 0);
        __builtin_amdgcn_s_setprio(0);
        __builtin_amdgcn_s_barrier();

        // ---- phase 3: stage tile t+2 into buf cur (all reads of cur are done:
        // p0-p2 ds_reads completed before p2's MFMA, barrier crossed). No ds_reads.
        // MFMA quad (mh1, n2-3). Boundary: counted vmcnt(8) -> tile t+1 landed,
        // t+2's 8 loads stay in flight across the barrier.
        if (t + 2 < GNT)
            stage_tile(X, W, sA[cur], sB[cur], m0, n0, (t + 2) * GBK, wave, lane);
        __builtin_amdgcn_s_barrier();
        __builtin_amdgcn_s_setprio(1);
#pragma unroll
        for (int mf = 0; mf < 4; ++mf)
#pragma unroll
            for (int nf = 2; nf < 4; ++nf)
#pragma unroll
                for (int kh = 0; kh < 2; ++kh)
                    acc[4 + mf][nf] = __builtin_amdgcn_mfma_f32_16x16x32_bf16(
                        a[mf][kh], b[nf][kh], acc[4 + mf][nf], 0, 0, 0);
        __builtin_amdgcn_s_setprio(0);
        if (t + 2 < GNT)
            asm volatile("s_waitcnt vmcnt(8)" ::: "memory");
        else
            asm volatile("s_waitcnt vmcnt(0)" ::: "memory");
        __builtin_amdgcn_s_barrier();
    }

    // epilogue: C/D layout col=lane&15, row=quad*4+reg
#pragma unroll
    for (int mf = 0; mf < 8; ++mf) {
        const int row = m0 + wm * 128 + mf * 16 + quad * 4;
#pragma unroll
        for (int nf = 0; nf < 4; ++nf) {
            const int col = n0 + wn * 64 + nf * 16 + lm;
#pragma unroll
            for (int r = 0; r < 4; ++r)
                Y[(long)(row + r) * DM_ + col] = acc[mf][nf][r];
        }
    }
}

// ---------------------------------------------------------------------------
extern "C" void kernel_launch(void* const* d_in, const int* in_sizes, int n_in,
                              void* d_out, int out_size, void* d_ws, size_t ws_size,
                              hipStream_t stream) {
    const float* Q   = (const float*)d_in[0];
    const float* K   = (const float*)d_in[1];
    const float* V   = (const float*)d_in[2];
    const float* L   = (const float*)d_in[3];
    const float* bal = (const float*)d_in[4];
    const float* Wo  = (const float*)d_in[5];
    float* Y = (float*)d_out;

    char* ws = (char*)d_ws;
    float* memory = (float*)ws;                                  // 8,388,608 B
    float* norm   = (float*)(ws + 8388608);                      //    65,536 B
    __hip_bfloat16* attnB = (__hip_bfloat16*)(ws + 8454144);     // 67,108,864 B
    __hip_bfloat16* woB   = (__hip_bfloat16*)(ws + 75563008);    // 33,554,432 B

    // zero the atomic accumulators (ws is poisoned 0xAA before every launch)
    hipMemsetAsync(memory, 0, 8454144, stream);

    k1_memory<<<dim3(4, BH_), 256, 0, stream>>>(K, V, memory, norm);
    kconv<<<DM_*DM_/4/256, 256, 0, stream>>>(Wo, woB);
    k2_retrieve<<<dim3(S_/32, BH_), 256, 0, stream>>>(Q, L, bal, memory, norm, attnB);
    k3_gemm<<<dim3(512), 512, 0, stream>>>(attnB, woB, Y);
}

// Round 3
// 888.642 us; speedup vs baseline: 1.3502x; 1.2086x over previous
//
#include <hip/hip_runtime.h>
#include <hip/hip_bf16.h>

#define B_ 4
#define H_ 32
#define S_ 2048
#define D_ 128
#define DM_ 4096
#define BH_ (B_*H_)
#define M_ (B_*S_)   // 8192 rows of final GEMM

typedef short bf16x8 __attribute__((ext_vector_type(8)));
typedef short s16x4  __attribute__((ext_vector_type(4)));
typedef float f32x4  __attribute__((ext_vector_type(4)));

__device__ __forceinline__ float phi_f(float x) {
    // elu(x)+1
    return x > 0.f ? x + 1.f : __expf(x);
}

__device__ __forceinline__ short f2b(float x) {
    __hip_bfloat16 h = __float2bfloat16(x);
    return *(short*)&h;
}

__device__ __forceinline__ void gl_lds16(void* lds_uniform, const void* gptr) {
    __builtin_amdgcn_global_load_lds(
        (const __attribute__((address_space(1))) void*)gptr,
        (__attribute__((address_space(3))) void*)lds_uniform,
        16, 0, 0);
}

// ---------------------------------------------------------------------------
// K1 (MFMA): memT[bh][v][k] = sum_s V[bh][s][v] * phi(K[bh][s][k])   (fp32, atomic)
//            nrm[bh][k]     = sum_s phi(K[bh][s][k])                 (fp32, atomic)
// grid (4 s-splits, 128 bh), 256 threads (4 waves, each a 64v x 64k quadrant).
// Per 64-s chunk: coalesced fp32 loads -> phi -> in-register 4x4 transpose ->
// bf16 ds_write into s-contiguous [128][72] tiles (pad 72 => LDS at BW floor).
// MFMA 16x16x32, contraction dim = s (contiguous in LDS).
// ---------------------------------------------------------------------------
__global__ __launch_bounds__(256) void k1_memory(
    const float* __restrict__ Kin, const float* __restrict__ Vin,
    float* __restrict__ memT, float* __restrict__ nrm)
{
    const int split = blockIdx.x;   // 0..3, 512 s-rows each
    const int bh = blockIdx.y;
    const int t = threadIdx.x;
    const int wave = t >> 6, lane = t & 63;
    const int lm = lane & 15, quad = lane >> 4;
    const int wm = wave >> 1, wn = wave & 1;    // v-half, k-half

    __shared__ __hip_bfloat16 sVt[128*72];      // [v][s]  18KB
    __shared__ __hip_bfloat16 sKt[128*72];      // [k][s]  18KB

    const long base = (long)bh * S_ * D_ + (long)split * (S_/4) * D_;
    const float* Kp = Kin + base;
    const float* Vp = Vin + base;

    f32x4 acc[4][4];
#pragma unroll
    for (int i = 0; i < 4; ++i)
#pragma unroll
        for (int j = 0; j < 4; ++j) { f32x4 z = {0.f,0.f,0.f,0.f}; acc[i][j] = z; }

    float na[2][4] = {{0.f,0.f,0.f,0.f},{0.f,0.f,0.f,0.f}};

    const int si  = t & 15;          // s-quad within chunk (0..15)
    const int dj0 = t >> 4;          // 0..15 (d-quad base)

    for (int c = 0; c < 8; ++c) {    // 8 chunks of 64 s-rows
        const int s0 = c*64 + si*4;
        __syncthreads();             // previous chunk's readers done
#pragma unroll
        for (int m = 0; m < 2; ++m) {
            const int dj = dj0 + 16*m;              // d-quad 0..31
            const float* gK = Kp + (long)s0*D_ + dj*4;
            const float* gV = Vp + (long)s0*D_ + dj*4;
            float4 krv[4], vrv[4];
#pragma unroll
            for (int r = 0; r < 4; ++r) {
                krv[r] = *(const float4*)(gK + (long)r*D_);
                vrv[r] = *(const float4*)(gV + (long)r*D_);
            }
            const float* kf = (const float*)krv;    // kf[r*4+cc]
            const float* vf = (const float*)vrv;
#pragma unroll
            for (int cc = 0; cc < 4; ++cc) {
                float p0 = phi_f(kf[0*4+cc]), p1 = phi_f(kf[1*4+cc]);
                float p2 = phi_f(kf[2*4+cc]), p3 = phi_f(kf[3*4+cc]);
                na[m][cc] += p0 + p1 + p2 + p3;
                s16x4 pw; pw[0]=f2b(p0); pw[1]=f2b(p1); pw[2]=f2b(p2); pw[3]=f2b(p3);
                s16x4 vw; vw[0]=f2b(vf[0*4+cc]); vw[1]=f2b(vf[1*4+cc]);
                          vw[2]=f2b(vf[2*4+cc]); vw[3]=f2b(vf[3*4+cc]);
                const int d = dj*4 + cc;
                *(s16x4*)(sKt + d*72 + si*4) = pw;
                *(s16x4*)(sVt + d*72 + si*4) = vw;
            }
        }
        __syncthreads();
#pragma unroll
        for (int kh = 0; kh < 2; ++kh) {
            const int scol = kh*32 + quad*8;
            bf16x8 af[4], bfr[4];
#pragma unroll
            for (int x = 0; x < 4; ++x) {
                af[x]  = *(const bf16x8*)(sVt + (wm*64 + x*16 + lm)*72 + scol);
                bfr[x] = *(const bf16x8*)(sKt + (wn*64 + x*16 + lm)*72 + scol);
            }
#pragma unroll
            for (int mt = 0; mt < 4; ++mt)
#pragma unroll
                for (int nt = 0; nt < 4; ++nt)
                    acc[mt][nt] = __builtin_amdgcn_mfma_f32_16x16x32_bf16(
                        af[mt], bfr[nt], acc[mt][nt], 0, 0, 0);
        }
    }

    // norm: reduce na over the 16 threads sharing dj (lane bits 0-3 = si)
#pragma unroll
    for (int m = 0; m < 2; ++m)
#pragma unroll
        for (int cc = 0; cc < 4; ++cc) {
            float v = na[m][cc];
            v += __shfl_xor(v, 1); v += __shfl_xor(v, 2);
            v += __shfl_xor(v, 4); v += __shfl_xor(v, 8);
            if (si == 0)
                atomicAdd(&nrm[bh*D_ + (dj0 + 16*m)*4 + cc], v);
        }

    // epilogue: C/D layout col = n (=k), row = m (=v): row = quad*4+reg
    float* mp = memT + (long)bh * D_ * D_;
#pragma unroll
    for (int mt = 0; mt < 4; ++mt)
#pragma unroll
        for (int nt = 0; nt < 4; ++nt) {
            const int kcol = wn*64 + nt*16 + lm;
#pragma unroll
            for (int r = 0; r < 4; ++r) {
                const int vrow = wm*64 + mt*16 + quad*4 + r;
                atomicAdd(&mp[vrow*D_ + kcol], acc[mt][nt][r]);
            }
        }
}

// ---------------------------------------------------------------------------
// K2 (MFMA): retrieved = phi(Q) @ mem ; denom = phi(Q)·norm ;
//            attn = gw*retrieved/denom + lw*local ; bf16 out to [B,S,H*D]
// grid (16 s-blocks of 128 rows, 128 bh), 256 threads (4 waves, 64s x 64v each).
// A = phi(Q) bf16 [s][k], B = memT bf16 [v][k] (k1 stored transposed), both in
// seg-XOR-swizzled LDS (seg' = seg ^ (row&15), 16B segs) -> reads at BW floor.
// denom computed fp32 during staging via 32-lane shfl reduce.
// ---------------------------------------------------------------------------
__global__ __launch_bounds__(256) void k2_retrieve(
    const float* __restrict__ Qin, const float* __restrict__ Lin,
    const float* __restrict__ bal,
    const float* __restrict__ memT, const float* __restrict__ nrm,
    __hip_bfloat16* __restrict__ attnB)
{
    const int sc = blockIdx.x;    // 0..15
    const int bh = blockIdx.y;
    const int b = bh >> 5, h = bh & 31;
    const int t = threadIdx.x;
    const int wave = t >> 6, lane = t & 63;
    const int lm = lane & 15, quad = lane >> 4;
    const int wm = wave >> 1, wn = wave & 1;    // s-half, v-half

    __shared__ __hip_bfloat16 sQ[128*128];      // 32KB [s][k] swizzled
    __shared__ __hip_bfloat16 sM[128*128];      // 32KB [v][k] swizzled
    __shared__ float sDen[128];

    const float* Qp = Qin + (long)bh*S_*D_ + (long)sc*128*D_;
    const float* Lp = Lin + (long)bh*S_*D_ + (long)sc*128*D_;
    const float* mp = memT + (long)bh*D_*D_;

    const int kq = t & 31;                       // k-quad (constant across i)
    const float4 nq = *(const float4*)(nrm + bh*D_ + kq*4);

#pragma unroll
    for (int i = 0; i < 16; ++i) {
        const int idx = t + i*256;               // float4 index over 128x32
        const int row = idx >> 5;                // = (t>>5) + 8i
        // --- Q: phi + denom partial + bf16 swizzled write
        float4 qv = *(const float4*)(Qp + (long)idx*4);
        float p0 = phi_f(qv.x), p1 = phi_f(qv.y), p2 = phi_f(qv.z), p3 = phi_f(qv.w);
        float part = p0*nq.x + p1*nq.y + p2*nq.z + p3*nq.w;
        part += __shfl_xor(part, 1);  part += __shfl_xor(part, 2);
        part += __shfl_xor(part, 4);  part += __shfl_xor(part, 8);
        part += __shfl_xor(part, 16);
        if (kq == 0) sDen[row] = part;
        const int seg = kq >> 1, half = kq & 1;
        const int off = row*128 + ((seg ^ (row & 15)) << 3) + half*4;
        s16x4 qw; qw[0]=f2b(p0); qw[1]=f2b(p1); qw[2]=f2b(p2); qw[3]=f2b(p3);
        *(s16x4*)(sQ + off) = qw;
        // --- memT: bf16 swizzled write (row = v here, same mapping)
        float4 mv = *(const float4*)(mp + (long)idx*4);
        s16x4 mw; mw[0]=f2b(mv.x); mw[1]=f2b(mv.y); mw[2]=f2b(mv.z); mw[3]=f2b(mv.w);
        *(s16x4*)(sM + off) = mw;
    }
    __syncthreads();

    f32x4 acc[4][4];
#pragma unroll
    for (int i = 0; i < 4; ++i)
#pragma unroll
        for (int j = 0; j < 4; ++j) { f32x4 z = {0.f,0.f,0.f,0.f}; acc[i][j] = z; }

#pragma unroll
    for (int kh = 0; kh < 4; ++kh) {
        const int segk = kh*4 + quad;            // 16B k-seg 0..15
        bf16x8 af[4], bfr[4];
#pragma unroll
        for (int x = 0; x < 4; ++x) {
            const int srow = wm*64 + x*16 + lm;
            af[x]  = *(const bf16x8*)(sQ + srow*128 + ((segk ^ (srow & 15)) << 3));
            const int vrow = wn*64 + x*16 + lm;
            bfr[x] = *(const bf16x8*)(sM + vrow*128 + ((segk ^ (vrow & 15)) << 3));
        }
#pragma unroll
        for (int mt = 0; mt < 4; ++mt)
#pragma unroll
            for (int nt = 0; nt < 4; ++nt)
                acc[mt][nt] = __builtin_amdgcn_mfma_f32_16x16x32_bf16(
                    af[mt], bfr[nt], acc[mt][nt], 0, 0, 0);
    }

    const float bv = bal[h];
    const float gw = 1.f/(1.f+__expf(-bv));
    const float lw = 1.f/(1.f+__expf(-(1.f-bv)));
#pragma unroll
    for (int mt = 0; mt < 4; ++mt)
#pragma unroll
        for (int r = 0; r < 4; ++r) {
            const int srow = wm*64 + mt*16 + quad*4 + r;
            const float scale = gw / sDen[srow];
            const long orow = (long)b*S_ + sc*128 + srow;
#pragma unroll
            for (int nt = 0; nt < 4; ++nt) {
                const int vcol = wn*64 + nt*16 + lm;
                const float lvv = Lp[(long)srow*D_ + vcol];
                const float o = acc[mt][nt][r]*scale + lw*lvv;
                attnB[orow*DM_ + h*D_ + vcol] = __float2bfloat16(o);
            }
        }
}

// ---------------------------------------------------------------------------
// w_o fp32 -> bf16
// ---------------------------------------------------------------------------
__global__ __launch_bounds__(256) void kconv(
    const float* __restrict__ w, __hip_bfloat16* __restrict__ wb)
{
    long i = ((long)blockIdx.x*256 + threadIdx.x)*4;
    float4 f = *(const float4*)(w + i);
    __hip_bfloat16 ob[4] = {__float2bfloat16(f.x), __float2bfloat16(f.y),
                            __float2bfloat16(f.z), __float2bfloat16(f.w)};
    *(uint2*)(wb + i) = *(uint2*)ob;
}

// ---------------------------------------------------------------------------
// K3: Y[8192,4096] = X[8192,4096] @ W[4096,4096]^T   (bf16 MFMA, fp32 out)
// 256x256 8-phase template: BK=64, 8 waves (2Mx4N), 512 threads, 128KiB LDS
// dbuf, counted vmcnt(8) at tile boundaries, raw s_barrier, setprio, seg-XOR
// swizzle (seg' = seg ^ (row&7)) via pre-swizzled global source. (unchanged)
// ---------------------------------------------------------------------------
#define GBM 256
#define GBN 256
#define GBK 64
#define GNT (DM_/GBK)   // 64 K-tiles

__device__ __forceinline__ bf16x8 ldfrag(const __hip_bfloat16* base, int row, int k) {
    const int kk = k ^ ((row & 7) << 3);
    return *(const bf16x8*)(base + row * GBK + kk);
}

__device__ __forceinline__ void stage_tile(
    const __hip_bfloat16* __restrict__ X, const __hip_bfloat16* __restrict__ W,
    __hip_bfloat16* sAb, __hip_bfloat16* sBb,
    int m0, int n0, int kb, int wave, int lane)
{
#pragma unroll
    for (int r = 0; r < 4; ++r) {
        const int c   = r * 512 + wave * 64 + lane;        // 16B chunk id 0..2047
        const int row = c >> 3;
        const int ko  = ((c & 7) ^ (row & 7)) * 8;         // pre-swizzled source seg
        gl_lds16((void*)(sAb + (r * 512 + wave * 64) * 8),
                 (const void*)(X + (long)(m0 + row) * DM_ + kb + ko));
    }
#pragma unroll
    for (int r = 0; r < 4; ++r) {
        const int c   = r * 512 + wave * 64 + lane;
        const int row = c >> 3;
        const int ko  = ((c & 7) ^ (row & 7)) * 8;
        gl_lds16((void*)(sBb + (r * 512 + wave * 64) * 8),
                 (const void*)(W + (long)(n0 + row) * DM_ + kb + ko));
    }
}

__global__ __launch_bounds__(512, 2) void k3_gemm(
    const __hip_bfloat16* __restrict__ X,
    const __hip_bfloat16* __restrict__ W,
    float* __restrict__ Y)
{
    __shared__ alignas(16) __hip_bfloat16 sA[2][GBM * GBK];   // 64 KiB
    __shared__ alignas(16) __hip_bfloat16 sB[2][GBN * GBK];   // 64 KiB

    const int tid = threadIdx.x;
    const int wave = tid >> 6, lane = tid & 63;
    const int lm = lane & 15, quad = lane >> 4;
    const int wm = wave >> 2, wn = wave & 3;     // 2M x 4N waves

    const int orig = blockIdx.x;
    const int wg = (orig & 7) * 64 + (orig >> 3);
    const int m0 = (wg >> 4) * GBM;
    const int n0 = (wg & 15) * GBN;

    f32x4 acc[8][4];
#pragma unroll
    for (int i = 0; i < 8; ++i)
#pragma unroll
        for (int j = 0; j < 4; ++j) { f32x4 z = {0.f,0.f,0.f,0.f}; acc[i][j] = z; }

    const int ar0 = wm * 128 + lm;
    const int br0 = wn * 64 + lm;
    const int kq  = quad * 8;

    stage_tile(X, W, sA[0], sB[0], m0, n0, 0, wave, lane);
    stage_tile(X, W, sA[1], sB[1], m0, n0, GBK, wave, lane);
    asm volatile("s_waitcnt vmcnt(8)" ::: "memory");
    __builtin_amdgcn_s_barrier();

    bf16x8 a[4][2], b[4][2];

    for (int t = 0; t < GNT; ++t) {
        const int cur = t & 1;
        const __hip_bfloat16* As = sA[cur];
        const __hip_bfloat16* Bs = sB[cur];

        // phase 0
#pragma unroll
        for (int mf = 0; mf < 4; ++mf)
#pragma unroll
            for (int kh = 0; kh < 2; ++kh)
                a[mf][kh] = ldfrag(As, ar0 + mf * 16, kh * 32 + kq);
#pragma unroll
        for (int nf = 0; nf < 2; ++nf)
#pragma unroll
            for (int kh = 0; kh < 2; ++kh)
                b[nf][kh] = ldfrag(Bs, br0 + nf * 16, kh * 32 + kq);
        __builtin_amdgcn_s_barrier();
        asm volatile("s_waitcnt lgkmcnt(0)" ::: "memory");
        __builtin_amdgcn_sched_barrier(0);
        __builtin_amdgcn_s_setprio(1);
#pragma unroll
        for (int mf = 0; mf < 4; ++mf)
#pragma unroll
            for (int nf = 0; nf < 2; ++nf)
#pragma unroll
                for (int kh = 0; kh < 2; ++kh)
                    acc[mf][nf] = __builtin_amdgcn_mfma_f32_16x16x32_bf16(
                        a[mf][kh], b[nf][kh], acc[mf][nf], 0, 0, 0);
        __builtin_amdgcn_s_setprio(0);
        __builtin_amdgcn_s_barrier();

        // phase 1
#pragma unroll
        for (int nf = 2; nf < 4; ++nf)
#pragma unroll
            for (int kh = 0; kh < 2; ++kh)
                b[nf][kh] = ldfrag(Bs, br0 + nf * 16, kh * 32 + kq);
        __builtin_amdgcn_s_barrier();
        asm volatile("s_waitcnt lgkmcnt(0)" ::: "memory");
        __builtin_amdgcn_sched_barrier(0);
        __builtin_amdgcn_s_setprio(1);
#pragma unroll
        for (int mf = 0; mf < 4; ++mf)
#pragma unroll
            for (int nf = 2; nf < 4; ++nf)
#pragma unroll
                for (int kh = 0; kh < 2; ++kh)
                    acc[mf][nf] = __builtin_amdgcn_mfma_f32_16x16x32_bf16(
                        a[mf][kh], b[nf][kh], acc[mf][nf], 0, 0, 0);
        __builtin_amdgcn_s_setprio(0);
        __builtin_amdgcn_s_barrier();

        // phase 2
#pragma unroll
        for (int mf = 0; mf < 4; ++mf)
#pragma unroll
            for (int kh = 0; kh < 2; ++kh)
                a[mf][kh] = ldfrag(As, ar0 + 64 + mf * 16, kh * 32 + kq);
        __builtin_amdgcn_s_barrier();
        asm volatile("s_waitcnt lgkmcnt(0)" ::: "memory");
        __builtin_amdgcn_sched_barrier(0);
        __builtin_amdgcn_s_setprio(1);
#pragma unroll
        for (int mf = 0; mf < 4; ++mf)
#pragma unroll
            for (int nf = 0; nf < 2; ++nf)
#pragma unroll
                for (int kh = 0; kh < 2; ++kh)
                    acc[4 + mf][nf] = __builtin_amdgcn_mfma_f32_16x16x32_bf16(
                        a[mf][kh], b[nf][kh], acc[4 + mf][nf], 0, 0, 0);
        __builtin_amdgcn_s_setprio(0);
        __builtin_amdgcn_s_barrier();

        // phase 3: stage t+2 into cur, counted vmcnt boundary
        if (t + 2 < GNT)
            stage_tile(X, W, sA[cur], sB[cur], m0, n0, (t + 2) * GBK, wave, lane);
        __builtin_amdgcn_s_barrier();
        __builtin_amdgcn_s_setprio(1);
#pragma unroll
        for (int mf = 0; mf < 4; ++mf)
#pragma unroll
            for (int nf = 2; nf < 4; ++nf)
#pragma unroll
                for (int kh = 0; kh < 2; ++kh)
                    acc[4 + mf][nf] = __builtin_amdgcn_mfma_f32_16x16x32_bf16(
                        a[mf][kh], b[nf][kh], acc[4 + mf][nf], 0, 0, 0);
        __builtin_amdgcn_s_setprio(0);
        if (t + 2 < GNT)
            asm volatile("s_waitcnt vmcnt(8)" ::: "memory");
        else
            asm volatile("s_waitcnt vmcnt(0)" ::: "memory");
        __builtin_amdgcn_s_barrier();
    }

#pragma unroll
    for (int mf = 0; mf < 8; ++mf) {
        const int row = m0 + wm * 128 + mf * 16 + quad * 4;
#pragma unroll
        for (int nf = 0; nf < 4; ++nf) {
            const int col = n0 + wn * 64 + nf * 16 + lm;
#pragma unroll
            for (int r = 0; r < 4; ++r)
                Y[(long)(row + r) * DM_ + col] = acc[mf][nf][r];
        }
    }
}

// ---------------------------------------------------------------------------
extern "C" void kernel_launch(void* const* d_in, const int* in_sizes, int n_in,
                              void* d_out, int out_size, void* d_ws, size_t ws_size,
                              hipStream_t stream) {
    const float* Q   = (const float*)d_in[0];
    const float* K   = (const float*)d_in[1];
    const float* V   = (const float*)d_in[2];
    const float* L   = (const float*)d_in[3];
    const float* bal = (const float*)d_in[4];
    const float* Wo  = (const float*)d_in[5];
    float* Y = (float*)d_out;

    char* ws = (char*)d_ws;
    float* memT  = (float*)ws;                                   // 8,388,608 B [bh][v][k]
    float* norm  = (float*)(ws + 8388608);                       //    65,536 B
    __hip_bfloat16* attnB = (__hip_bfloat16*)(ws + 8454144);     // 67,108,864 B
    __hip_bfloat16* woB   = (__hip_bfloat16*)(ws + 75563008);    // 33,554,432 B

    // zero the atomic accumulators (ws is poisoned 0xAA before every launch)
    hipMemsetAsync(memT, 0, 8454144, stream);

    k1_memory<<<dim3(4, BH_), 256, 0, stream>>>(K, V, memT, norm);
    kconv<<<DM_*DM_/4/256, 256, 0, stream>>>(Wo, woB);
    k2_retrieve<<<dim3(S_/128, BH_), 256, 0, stream>>>(Q, L, bal, memT, norm, attnB);
    k3_gemm<<<dim3(512), 512, 0, stream>>>(attnB, woB, Y);
}